// Round 9
// baseline (444.783 us; speedup 1.0000x reference)
//
#include <hip/hip_runtime.h>

#define NN 100000
#define NE 800000
#define BCAP 32  // bucket capacity per dst; deg ~ Poisson(8), P(deg>32) ~ 2.5e-11/node

static constexpr int NBT = (NN + 63) / 64;  // node-tile blocks = 1563

typedef __attribute__((ext_vector_type(8))) short short8;
typedef __attribute__((ext_vector_type(4))) float f32x4;

__device__ __forceinline__ unsigned short f2bf(float f) {
  unsigned int u = __float_as_uint(f);
  u += 0x7fffu + ((u >> 16) & 1u);
  return (unsigned short)(u >> 16);
}
__device__ __forceinline__ float bflo(unsigned int u) { return __uint_as_float(u << 16); }
__device__ __forceinline__ float bfhi(unsigned int u) { return __uint_as_float(u & 0xffff0000u); }

// ---------------- prep: x->bf16 + W->bf16 B-frag (pure convert, no atomics) -----------

__global__ void k_prep(const float* __restrict__ x, unsigned short* __restrict__ hb,
                       const float* __restrict__ Wl, const float* __restrict__ Wr,
                       unsigned short* __restrict__ Wb, const float* __restrict__ Wf,
                       unsigned short* __restrict__ Wfb) {
  int i = blockIdx.x * 256 + threadIdx.x;
  long long base = (long long)i * 4;
  if (base < (long long)NN * 128) {
    float4 v = *(const float4*)(x + base);
    unsigned long long pk = (unsigned long long)f2bf(v.x) |
                            ((unsigned long long)f2bf(v.y) << 16) |
                            ((unsigned long long)f2bf(v.z) << 32) |
                            ((unsigned long long)f2bf(v.w) << 48);
    *(unsigned long long*)(hb + base) = pk;
  }
  if (i < 3 * 16384) {
    int layer = i >> 14, r = i & 16383;
    int j = r >> 7, k = r & 127;
    int c = k >> 5, q = (k >> 3) & 3, jj = k & 7, jt = j >> 4, j16 = j & 15;
    int slot = (c * 8 + jt) * 512 + (q * 16 + j16) * 8 + jj;
    Wb[layer * 32768 + slot] = f2bf(Wl[i]);
    Wb[layer * 32768 + 16384 + slot] = f2bf(Wr[i]);
  } else if (i < 3 * 16384 + 8192) {
    int idx = i - 3 * 16384;
    int j = idx >> 7, k = idx & 127;
    int c = k >> 5, q = (k >> 3) & 3, jj = k & 7, jt = j >> 4, j16 = j & 15;
    Wfb[(c * 4 + jt) * 512 + (q * 16 + j16) * 8 + jj] = f2bf(Wf[idx]);
  }
}

// ---------------- bucket-CSR fill: one atomic per edge, no scan, no merge -------------

__global__ void k_fill(const int* __restrict__ ei, int* __restrict__ cnt,
                       int* __restrict__ col) {
  int e = blockIdx.x * 256 + threadIdx.x;
  if (e < NE) {
    int d = ei[e];
    int pos = atomicAdd(&cnt[d], 1);
    if (pos < BCAP) col[(size_t)d * BCAP + pos] = ei[NE + e];
  }
}

// ---------------- fused SAGE layer (+ fused final head when LAST) ----------------
// block = 256 (4 waves), 64 nodes/block (16/wave).
// Gather: WAVE-per-node, lane = feature pair (4B/lane, one row = one wave-load).
// The wave's 16 nodes are walked as a FLAT edge list with a depth-16 register
// ring -> 16 rows (4KB) in flight per wave, zero divergence (cursors uniform).
// (256,4): 128 regs/wave — (256,7) spilled in r6.
template <bool LAST>
__global__ __launch_bounds__(256, 4)
void k_layer(const unsigned short* __restrict__ hin, unsigned short* __restrict__ hout,
             const int* __restrict__ deg, const int* __restrict__ col,
             const unsigned short* __restrict__ Wb, const float* __restrict__ bl,
             const float* __restrict__ gmm, const float* __restrict__ bta,
             const unsigned short* __restrict__ Wfb, const float* __restrict__ bfp,
             float* __restrict__ out) {
  __shared__ int colS[64 * BCAP];           // 8192B
  __shared__ int degS[64];                  //  256B
  __shared__ unsigned short aggS[64 * 136]; // 17408B ; overlaid by hS in LAST tail
  const int t = threadIdx.x;
  const int w = t >> 6;
  const int lane = t & 63;
  const int nodeBase = blockIdx.x * 64;
  const int q = lane >> 4;
  const int n16 = lane & 15;

  // prefetch own-row h A-frags (independent of gather)
  int nrow = nodeBase + w * 16 + n16;
  const unsigned short* hrow = hin + (size_t)(nrow < NN ? nrow : NN - 1) * 128;
  short8 a_h[4];
#pragma unroll
  for (int c = 0; c < 4; ++c) a_h[c] = *(const short8*)(hrow + c * 32 + q * 8);

  // stage degrees + bucket window (contiguous 8KB -> 2 int4 per thread)
  if (t < 64) {
    int n = nodeBase + t;
    degS[t] = (n < NN) ? deg[n] : 0;
  }
  {
    const int4* src = (const int4*)(col + (size_t)nodeBase * BCAP);
#pragma unroll
    for (int i = 0; i < 2; ++i) *((int4*)colS + t + i * 256) = src[t + i * 256];
  }
  __syncthreads();

  // --- flat-list wave-per-node gather, depth-16 ring ---
  const unsigned int* hin32 = (const unsigned int*)hin;
  // per-wave clamped degrees on lanes 0..15; wave edge total Ew
  int dcl = 0;
  if (lane < 16) {
    dcl = degS[w * 16 + lane];
    if (dcl > BCAP) dcl = BCAP;
  }
  int sv = dcl;
#pragma unroll
  for (int off = 1; off < 16; off <<= 1) {
    int u = __shfl_up(sv, off, 64);
    if (lane >= off) sv += u;
  }
  const int Ew = __shfl(sv, 15, 64);

  unsigned int vr[16];
  int inode = 0, iofs = 0;   // issue cursor (wave-uniform)
  int dnode = 0, dofs = 0;   // drain cursor (wave-uniform)
  float ax = 0.f, ay = 0.f;

  auto dOf = [&](int i) { return __shfl(dcl, i, 64); };
  auto writeRow = [&](int node, unsigned int packed) {
    *(unsigned int*)&aggS[(w * 16 + node) * 136 + lane * 2] = packed;
  };
  auto issue = [&]() {
    while (iofs == dOf(inode)) { ++inode; iofs = 0; }
    int s = colS[(w * 16 + inode) * BCAP + iofs];
    ++iofs;
    return hin32[(size_t)s * 64 + lane];
  };
  // leading zero-degree nodes -> zero rows
  while (dnode < 16 && dOf(dnode) == 0) { writeRow(dnode, 0u); ++dnode; }

#pragma unroll
  for (int k = 0; k < 16; ++k)
    if (k < Ew) vr[k] = issue();

  for (int basei = 0; basei < Ew; basei += 16) {
#pragma unroll
    for (int k = 0; k < 16; ++k) {
      int i = basei + k;
      if (i < Ew) {
        unsigned int u = vr[k];
        ax += bflo(u);
        ay += bfhi(u);
        ++dofs;
        if (dofs == dOf(dnode)) {
          float inv = 1.f / (float)degS[w * 16 + dnode];  // deg>0 here
          unsigned int packed =
              ((unsigned int)f2bf(ay * inv) << 16) | (unsigned int)f2bf(ax * inv);
          writeRow(dnode, packed);
          ax = 0.f; ay = 0.f; dofs = 0; ++dnode;
          while (dnode < 16 && dOf(dnode) == 0) { writeRow(dnode, 0u); ++dnode; }
        }
        if (i + 16 < Ew) vr[k] = issue();
      }
    }
  }
  __syncthreads();

  // MFMA: wave handles 16 nodes x 128 out; B-frags from prepped global (L2)
  f32x4 acc[8];
#pragma unroll
  for (int jt = 0; jt < 8; ++jt) acc[jt] = (f32x4){0.f, 0.f, 0.f, 0.f};
  const unsigned short* aggrow = aggS + (w * 16 + n16) * 136;
#pragma unroll
  for (int c = 0; c < 4; ++c) {
    short8 a_agg = *(const short8*)(aggrow + c * 32 + q * 8);
#pragma unroll
    for (int jt = 0; jt < 8; ++jt) {
      short8 b_l = *(const short8*)(Wb + (c * 8 + jt) * 512 + lane * 8);
      short8 b_r = *(const short8*)(Wb + 16384 + (c * 8 + jt) * 512 + lane * 8);
      acc[jt] = __builtin_amdgcn_mfma_f32_16x16x32_bf16(a_agg, b_l, acc[jt], 0, 0, 0);
      acc[jt] = __builtin_amdgcn_mfma_f32_16x16x32_bf16(a_h[c], b_r, acc[jt], 0, 0, 0);
    }
  }

  // epilogue: +bias, LayerNorm (xor-shuffle over 16-lane groups), ReLU
  float blv[8], gv[8], bv[8];
#pragma unroll
  for (int jt = 0; jt < 8; ++jt) {
    int j = jt * 16 + n16;
    blv[jt] = bl[j];
    gv[jt] = gmm[j];
    bv[jt] = bta[j];
  }
  float s[4] = {0, 0, 0, 0}, ss[4] = {0, 0, 0, 0};
#pragma unroll
  for (int jt = 0; jt < 8; ++jt)
#pragma unroll
    for (int r = 0; r < 4; ++r) {
      float v = acc[jt][r] + blv[jt];
      acc[jt][r] = v;
      s[r] += v;
      ss[r] += v * v;
    }
#pragma unroll
  for (int mask = 1; mask < 16; mask <<= 1) {
#pragma unroll
    for (int r = 0; r < 4; ++r) {
      s[r] += __shfl_xor(s[r], mask, 64);
      ss[r] += __shfl_xor(ss[r], mask, 64);
    }
  }
  float mu[4], rs[4];
#pragma unroll
  for (int r = 0; r < 4; ++r) {
    mu[r] = s[r] * (1.f / 128.f);
    float var = ss[r] * (1.f / 128.f) - mu[r] * mu[r];
    rs[r] = rsqrtf(var + 1e-5f);
  }

  if (!LAST) {
#pragma unroll
    for (int jt = 0; jt < 8; ++jt)
#pragma unroll
      for (int r = 0; r < 4; ++r) {
        int n = nodeBase + w * 16 + q * 4 + r;
        if (n < NN) {
          float v = (acc[jt][r] - mu[r]) * rs[r] * gv[jt] + bv[jt];
          hout[(size_t)n * 128 + jt * 16 + n16] = f2bf(fmaxf(v, 0.f));
        }
      }
  } else {
    unsigned short* hS = aggS;  // overlay
    __syncthreads();            // all aggS reads done before overlay write
#pragma unroll
    for (int jt = 0; jt < 8; ++jt)
#pragma unroll
      for (int r = 0; r < 4; ++r) {
        float v = (acc[jt][r] - mu[r]) * rs[r] * gv[jt] + bv[jt];
        hS[(w * 16 + q * 4 + r) * 136 + jt * 16 + n16] = f2bf(fmaxf(v, 0.f));
      }
    // final 128x64 GEMM + log_softmax (same-wave rows only)
    f32x4 acc2[4];
#pragma unroll
    for (int jt = 0; jt < 4; ++jt) acc2[jt] = (f32x4){0.f, 0.f, 0.f, 0.f};
#pragma unroll
    for (int c = 0; c < 4; ++c) {
      short8 a3 = *(const short8*)&hS[(w * 16 + n16) * 136 + c * 32 + q * 8];
#pragma unroll
      for (int jt = 0; jt < 4; ++jt) {
        short8 b = *(const short8*)(Wfb + (c * 4 + jt) * 512 + lane * 8);
        acc2[jt] = __builtin_amdgcn_mfma_f32_16x16x32_bf16(a3, b, acc2[jt], 0, 0, 0);
      }
    }
    float bfv[4];
#pragma unroll
    for (int jt = 0; jt < 4; ++jt) bfv[jt] = bfp[jt * 16 + n16];
    float mx[4] = {-1e30f, -1e30f, -1e30f, -1e30f};
#pragma unroll
    for (int jt = 0; jt < 4; ++jt)
#pragma unroll
      for (int r = 0; r < 4; ++r) {
        float v = acc2[jt][r] + bfv[jt];
        acc2[jt][r] = v;
        mx[r] = fmaxf(mx[r], v);
      }
#pragma unroll
    for (int mask = 1; mask < 16; mask <<= 1)
#pragma unroll
      for (int r = 0; r < 4; ++r) mx[r] = fmaxf(mx[r], __shfl_xor(mx[r], mask, 64));
    float se[4] = {0, 0, 0, 0};
#pragma unroll
    for (int jt = 0; jt < 4; ++jt)
#pragma unroll
      for (int r = 0; r < 4; ++r) se[r] += expf(acc2[jt][r] - mx[r]);
#pragma unroll
    for (int mask = 1; mask < 16; mask <<= 1)
#pragma unroll
      for (int r = 0; r < 4; ++r) se[r] += __shfl_xor(se[r], mask, 64);
    float lse[4];
#pragma unroll
    for (int r = 0; r < 4; ++r) lse[r] = mx[r] + logf(se[r]);
#pragma unroll
    for (int jt = 0; jt < 4; ++jt)
#pragma unroll
      for (int r = 0; r < 4; ++r) {
        int n = nodeBase + w * 16 + q * 4 + r;
        if (n < NN) out[(size_t)n * 64 + jt * 16 + n16] = acc2[jt][r] - lse[r];
      }
  }
}

// ---------------- launch ----------------

extern "C" void kernel_launch(void* const* d_in, const int* in_sizes, int n_in,
                              void* d_out, int out_size, void* d_ws, size_t ws_size,
                              hipStream_t stream) {
  const float* x = (const float*)d_in[0];
  const int* ei = (const int*)d_in[1];
  const float* Wl = (const float*)d_in[2];
  const float* bl = (const float*)d_in[3];
  const float* Wr = (const float*)d_in[4];
  const float* gmm = (const float*)d_in[5];
  const float* bta = (const float*)d_in[6];
  const float* Wf = (const float*)d_in[7];
  const float* bfp = (const float*)d_in[8];

  char* ws = (char*)d_ws;
  size_t off = 0;
  auto alloc = [&](size_t bytes) {
    void* p = ws + off;
    off = (off + bytes + 255) & ~(size_t)255;
    return p;
  };
  int* cnt = (int*)alloc((size_t)(NN + 64) * 4);            // degree (atomic cursor)
  int* col = (int*)alloc((size_t)(NN + 64) * BCAP * 4);     // bucketed CSR (pad for last tile)
  unsigned short* hb0 = (unsigned short*)alloc((size_t)NN * 128 * 2);
  unsigned short* hb1 = (unsigned short*)alloc((size_t)NN * 128 * 2);
  unsigned short* Wb = (unsigned short*)alloc((size_t)3 * 32768 * 2);
  unsigned short* Wfb = (unsigned short*)alloc((size_t)8192 * 2);

  hipMemsetAsync(cnt, 0, (size_t)(NN + 64) * 4, stream);
  k_prep<<<(NN * 128 / 4 + 255) / 256, 256, 0, stream>>>(x, hb0, Wl, Wr, Wb, Wf, Wfb);
  k_fill<<<(NE + 255) / 256, 256, 0, stream>>>(ei, cnt, col);

  k_layer<false><<<NBT, 256, 0, stream>>>(hb0, hb1, cnt, col, Wb, bl, gmm, bta, Wfb, bfp,
                                          (float*)d_out);
  k_layer<false><<<NBT, 256, 0, stream>>>(hb1, hb0, cnt, col, Wb + 32768, bl + 128,
                                          gmm + 128, bta + 128, Wfb, bfp, (float*)d_out);
  k_layer<true><<<NBT, 256, 0, stream>>>(hb0, hb1, cnt, col, Wb + 65536, bl + 256,
                                         gmm + 256, bta + 256, Wfb, bfp, (float*)d_out);
}

// Round 10
// 323.223 us; speedup vs baseline: 1.3761x; 1.3761x over previous
//
#include <hip/hip_runtime.h>

#define NN 100000
#define NE 800000
#define BCAP 32  // bucket capacity per dst; deg ~ Poisson(8), P(deg>32) ~ 2.5e-11/node

static constexpr int NBT = (NN + 31) / 32;  // node-tile blocks (32 nodes) = 3125

typedef __attribute__((ext_vector_type(8))) short short8;
typedef __attribute__((ext_vector_type(4))) float f32x4;
struct U2 { unsigned long long x, y; };

__device__ __forceinline__ unsigned short f2bf(float f) {
  unsigned int u = __float_as_uint(f);
  u += 0x7fffu + ((u >> 16) & 1u);
  return (unsigned short)(u >> 16);
}
__device__ __forceinline__ float bflo(unsigned int u) { return __uint_as_float(u << 16); }
__device__ __forceinline__ float bfhi(unsigned int u) { return __uint_as_float(u & 0xffff0000u); }

__device__ __forceinline__ void acc8(const U2& v, float* a) {
  unsigned int w0 = (unsigned int)v.x, w1 = (unsigned int)(v.x >> 32);
  unsigned int w2 = (unsigned int)v.y, w3 = (unsigned int)(v.y >> 32);
  a[0] += bflo(w0); a[1] += bfhi(w0); a[2] += bflo(w1); a[3] += bfhi(w1);
  a[4] += bflo(w2); a[5] += bfhi(w2); a[6] += bflo(w3); a[7] += bfhi(w3);
}

// ------------- fused prep+fill: x->bf16, W->bf16 B-frag, bucket-CSR fill --------------
// B-frag slot for 16x16x32: lane=q*16+j16 holds B[k=c*32+q*8+jj][j=jt*16+j16]

__global__ void k_prep_fill(const float* __restrict__ x, unsigned short* __restrict__ hb,
                            const int* __restrict__ ei, int* __restrict__ cnt,
                            int* __restrict__ col, const float* __restrict__ Wl,
                            const float* __restrict__ Wr, unsigned short* __restrict__ Wb,
                            const float* __restrict__ Wf, unsigned short* __restrict__ Wfb) {
  int i = blockIdx.x * 256 + threadIdx.x;
  long long base = (long long)i * 4;
  if (base < (long long)NN * 128) {
    float4 v = *(const float4*)(x + base);
    unsigned long long pk = (unsigned long long)f2bf(v.x) |
                            ((unsigned long long)f2bf(v.y) << 16) |
                            ((unsigned long long)f2bf(v.z) << 32) |
                            ((unsigned long long)f2bf(v.w) << 48);
    *(unsigned long long*)(hb + base) = pk;
  }
  if (i < NE) {
    int d = ei[i];
    int pos = atomicAdd(&cnt[d], 1);
    if (pos < BCAP) col[(size_t)d * BCAP + pos] = ei[NE + i];
  }
  if (i < 3 * 16384) {
    int layer = i >> 14, r = i & 16383;
    int j = r >> 7, k = r & 127;
    int c = k >> 5, q = (k >> 3) & 3, jj = k & 7, jt = j >> 4, j16 = j & 15;
    int slot = (c * 8 + jt) * 512 + (q * 16 + j16) * 8 + jj;
    Wb[layer * 32768 + slot] = f2bf(Wl[i]);
    Wb[layer * 32768 + 16384 + slot] = f2bf(Wr[i]);
  } else if (i < 3 * 16384 + 8192) {
    int idx = i - 3 * 16384;
    int j = idx >> 7, k = idx & 127;
    int c = k >> 5, q = (k >> 3) & 3, jj = k & 7, jt = j >> 4, j16 = j & 15;
    Wfb[(c * 4 + jt) * 512 + (q * 16 + j16) * 8 + jj] = f2bf(Wf[idx]);
  }
}

// ---------------- fused SAGE layer (+ fused final head when LAST) ----------------
// block = 128 threads (2 waves), 32 nodes/block (16/wave). LDS ~13.3KB ->
// 12 blocks/CU (24 waves, 75% ceiling) at __launch_bounds__(128,6) — occupancy is
// the lever: gather is latency-bound (r3 62us @43% vs r8 73us @35%).
// Gather: 16-lane group per node (4/wave concurrent), 16B/lane, depth-4 pipeline.
template <bool LAST>
__global__ __launch_bounds__(128, 6)
void k_layer(const unsigned short* __restrict__ hin, unsigned short* __restrict__ hout,
             const int* __restrict__ deg, const int* __restrict__ col,
             const unsigned short* __restrict__ Wb, const float* __restrict__ bl,
             const float* __restrict__ gmm, const float* __restrict__ bta,
             const unsigned short* __restrict__ Wfb, const float* __restrict__ bfp,
             float* __restrict__ out) {
  __shared__ int colS[32 * BCAP];           // 4096B
  __shared__ int degS[32];                  //  128B
  __shared__ unsigned short aggS[32 * 136]; // 8704B ; overlaid by hS in LAST tail
  const int t = threadIdx.x;
  const int w = t >> 6;
  const int lane = t & 63;
  const int nodeBase = blockIdx.x * 32;
  const int q = lane >> 4;
  const int n16 = lane & 15;

  // prefetch own-row h A-frags (independent of gather)
  int nrow = nodeBase + w * 16 + n16;
  const unsigned short* hrow = hin + (size_t)(nrow < NN ? nrow : NN - 1) * 128;
  short8 a_h[4];
#pragma unroll
  for (int c = 0; c < 4; ++c) a_h[c] = *(const short8*)(hrow + c * 32 + q * 8);

  // stage degrees + bucket window (contiguous 4KB -> 2 int4 per thread)
  if (t < 32) {
    int n = nodeBase + t;
    degS[t] = (n < NN) ? deg[n] : 0;
  }
  {
    const int4* src = (const int4*)(col + (size_t)nodeBase * BCAP);
#pragma unroll
    for (int i = 0; i < 2; ++i) *((int4*)colS + t + i * 128) = src[t + i * 128];
  }
  __syncthreads();

  // gather: 16-lane group per node (4 concurrent per wave), depth-4 pipeline
  const int grp = lane >> 4;
  const int jl = lane & 15;
  auto rowAt = [&](int s) { return *(const U2*)(hin + (size_t)s * 128 + jl * 8); };
#pragma unroll
  for (int mm = 0; mm < 4; ++mm) {
    int li = w * 16 + mm * 4 + grp;
    int d = degS[li];
    if (d > BCAP) d = BCAP;
    float inv = 1.f / fmaxf((float)degS[li], 1.f);
    float a[8] = {0.f, 0.f, 0.f, 0.f, 0.f, 0.f, 0.f, 0.f};
    const int* bucket = colS + li * BCAP;
    int j = 0;
    for (; j + 4 <= d; j += 4) {
      U2 v0 = rowAt(bucket[j + 0]);
      U2 v1 = rowAt(bucket[j + 1]);
      U2 v2 = rowAt(bucket[j + 2]);
      U2 v3 = rowAt(bucket[j + 3]);
      acc8(v0, a); acc8(v1, a); acc8(v2, a); acc8(v3, a);
    }
    for (; j < d; ++j) { U2 v = rowAt(bucket[j]); acc8(v, a); }
    unsigned int p0 = ((unsigned int)f2bf(a[1] * inv) << 16) | f2bf(a[0] * inv);
    unsigned int p1 = ((unsigned int)f2bf(a[3] * inv) << 16) | f2bf(a[2] * inv);
    unsigned int p2 = ((unsigned int)f2bf(a[5] * inv) << 16) | f2bf(a[4] * inv);
    unsigned int p3 = ((unsigned int)f2bf(a[7] * inv) << 16) | f2bf(a[6] * inv);
    *(uint4*)&aggS[li * 136 + jl * 8] = make_uint4(p0, p1, p2, p3);
  }
  __syncthreads();

  // MFMA: wave handles 16 nodes x 128 out; B-frags from prepped global (L2)
  f32x4 acc[8];
#pragma unroll
  for (int jt = 0; jt < 8; ++jt) acc[jt] = (f32x4){0.f, 0.f, 0.f, 0.f};
  const unsigned short* aggrow = aggS + (w * 16 + n16) * 136;
#pragma unroll
  for (int c = 0; c < 4; ++c) {
    short8 a_agg = *(const short8*)(aggrow + c * 32 + q * 8);
#pragma unroll
    for (int jt = 0; jt < 8; ++jt) {
      short8 b_l = *(const short8*)(Wb + (c * 8 + jt) * 512 + lane * 8);
      short8 b_r = *(const short8*)(Wb + 16384 + (c * 8 + jt) * 512 + lane * 8);
      acc[jt] = __builtin_amdgcn_mfma_f32_16x16x32_bf16(a_agg, b_l, acc[jt], 0, 0, 0);
      acc[jt] = __builtin_amdgcn_mfma_f32_16x16x32_bf16(a_h[c], b_r, acc[jt], 0, 0, 0);
    }
  }

  // epilogue: +bias, LayerNorm (xor-shuffle over 16-lane groups), ReLU
  float blv[8], gv[8], bv[8];
#pragma unroll
  for (int jt = 0; jt < 8; ++jt) {
    int j = jt * 16 + n16;
    blv[jt] = bl[j];
    gv[jt] = gmm[j];
    bv[jt] = bta[j];
  }
  float s[4] = {0, 0, 0, 0}, ss[4] = {0, 0, 0, 0};
#pragma unroll
  for (int jt = 0; jt < 8; ++jt)
#pragma unroll
    for (int r = 0; r < 4; ++r) {
      float v = acc[jt][r] + blv[jt];
      acc[jt][r] = v;
      s[r] += v;
      ss[r] += v * v;
    }
#pragma unroll
  for (int mask = 1; mask < 16; mask <<= 1) {
#pragma unroll
    for (int r = 0; r < 4; ++r) {
      s[r] += __shfl_xor(s[r], mask, 64);
      ss[r] += __shfl_xor(ss[r], mask, 64);
    }
  }
  float mu[4], rs[4];
#pragma unroll
  for (int r = 0; r < 4; ++r) {
    mu[r] = s[r] * (1.f / 128.f);
    float var = ss[r] * (1.f / 128.f) - mu[r] * mu[r];
    rs[r] = rsqrtf(var + 1e-5f);
  }

  if (!LAST) {
#pragma unroll
    for (int jt = 0; jt < 8; ++jt)
#pragma unroll
      for (int r = 0; r < 4; ++r) {
        int n = nodeBase + w * 16 + q * 4 + r;
        if (n < NN) {
          float v = (acc[jt][r] - mu[r]) * rs[r] * gv[jt] + bv[jt];
          hout[(size_t)n * 128 + jt * 16 + n16] = f2bf(fmaxf(v, 0.f));
        }
      }
  } else {
    unsigned short* hS = aggS;  // overlay (each wave touches only its own 16 rows)
    __syncthreads();
#pragma unroll
    for (int jt = 0; jt < 8; ++jt)
#pragma unroll
      for (int r = 0; r < 4; ++r) {
        float v = (acc[jt][r] - mu[r]) * rs[r] * gv[jt] + bv[jt];
        hS[(w * 16 + q * 4 + r) * 136 + jt * 16 + n16] = f2bf(fmaxf(v, 0.f));
      }
    // final 128x64 GEMM + log_softmax (same-wave rows only)
    f32x4 acc2[4];
#pragma unroll
    for (int jt = 0; jt < 4; ++jt) acc2[jt] = (f32x4){0.f, 0.f, 0.f, 0.f};
#pragma unroll
    for (int c = 0; c < 4; ++c) {
      short8 a3 = *(const short8*)&hS[(w * 16 + n16) * 136 + c * 32 + q * 8];
#pragma unroll
      for (int jt = 0; jt < 4; ++jt) {
        short8 b = *(const short8*)(Wfb + (c * 4 + jt) * 512 + lane * 8);
        acc2[jt] = __builtin_amdgcn_mfma_f32_16x16x32_bf16(a3, b, acc2[jt], 0, 0, 0);
      }
    }
    float bfv[4];
#pragma unroll
    for (int jt = 0; jt < 4; ++jt) bfv[jt] = bfp[jt * 16 + n16];
    float mx[4] = {-1e30f, -1e30f, -1e30f, -1e30f};
#pragma unroll
    for (int jt = 0; jt < 4; ++jt)
#pragma unroll
      for (int r = 0; r < 4; ++r) {
        float v = acc2[jt][r] + bfv[jt];
        acc2[jt][r] = v;
        mx[r] = fmaxf(mx[r], v);
      }
#pragma unroll
    for (int mask = 1; mask < 16; mask <<= 1)
#pragma unroll
      for (int r = 0; r < 4; ++r) mx[r] = fmaxf(mx[r], __shfl_xor(mx[r], mask, 64));
    float se[4] = {0, 0, 0, 0};
#pragma unroll
    for (int jt = 0; jt < 4; ++jt)
#pragma unroll
      for (int r = 0; r < 4; ++r) se[r] += expf(acc2[jt][r] - mx[r]);
#pragma unroll
    for (int mask = 1; mask < 16; mask <<= 1)
#pragma unroll
      for (int r = 0; r < 4; ++r) se[r] += __shfl_xor(se[r], mask, 64);
    float lse[4];
#pragma unroll
    for (int r = 0; r < 4; ++r) lse[r] = mx[r] + logf(se[r]);
#pragma unroll
    for (int jt = 0; jt < 4; ++jt)
#pragma unroll
      for (int r = 0; r < 4; ++r) {
        int n = nodeBase + w * 16 + q * 4 + r;
        if (n < NN) out[(size_t)n * 64 + jt * 16 + n16] = acc2[jt][r] - lse[r];
      }
  }
}

// ---------------- launch ----------------

extern "C" void kernel_launch(void* const* d_in, const int* in_sizes, int n_in,
                              void* d_out, int out_size, void* d_ws, size_t ws_size,
                              hipStream_t stream) {
  const float* x = (const float*)d_in[0];
  const int* ei = (const int*)d_in[1];
  const float* Wl = (const float*)d_in[2];
  const float* bl = (const float*)d_in[3];
  const float* Wr = (const float*)d_in[4];
  const float* gmm = (const float*)d_in[5];
  const float* bta = (const float*)d_in[6];
  const float* Wf = (const float*)d_in[7];
  const float* bfp = (const float*)d_in[8];

  char* ws = (char*)d_ws;
  size_t off = 0;
  auto alloc = [&](size_t bytes) {
    void* p = ws + off;
    off = (off + bytes + 255) & ~(size_t)255;
    return p;
  };
  int* cnt = (int*)alloc((size_t)(NN + 32) * 4);          // degree (atomic cursor)
  int* col = (int*)alloc((size_t)(NN + 32) * BCAP * 4);   // bucketed CSR (pad last tile)
  unsigned short* hb0 = (unsigned short*)alloc((size_t)NN * 128 * 2);
  unsigned short* hb1 = (unsigned short*)alloc((size_t)NN * 128 * 2);
  unsigned short* Wb = (unsigned short*)alloc((size_t)3 * 32768 * 2);
  unsigned short* Wfb = (unsigned short*)alloc((size_t)8192 * 2);

  hipMemsetAsync(cnt, 0, (size_t)(NN + 32) * 4, stream);
  k_prep_fill<<<(NN * 128 / 4 + 255) / 256, 256, 0, stream>>>(x, hb0, ei, cnt, col, Wl,
                                                              Wr, Wb, Wf, Wfb);

  k_layer<false><<<NBT, 128, 0, stream>>>(hb0, hb1, cnt, col, Wb, bl, gmm, bta, Wfb, bfp,
                                          (float*)d_out);
  k_layer<false><<<NBT, 128, 0, stream>>>(hb1, hb0, cnt, col, Wb + 32768, bl + 128,
                                          gmm + 128, bta + 128, Wfb, bfp, (float*)d_out);
  k_layer<true><<<NBT, 128, 0, stream>>>(hb0, hb1, cnt, col, Wb + 65536, bl + 256,
                                         gmm + 256, bta + 256, Wfb, bfp, (float*)d_out);
}

// Round 11
// 323.217 us; speedup vs baseline: 1.3761x; 1.0000x over previous
//
#include <hip/hip_runtime.h>

#define NN 100000
#define NE 800000
#define BCAP 32  // bucket capacity per dst; deg ~ Poisson(8), P(deg>32) ~ 2.5e-11/node

static constexpr int NBT = NN / 32;  // node-tile blocks (32 nodes) = 3125, exact

typedef __attribute__((ext_vector_type(8))) short short8;
typedef __attribute__((ext_vector_type(4))) float f32x4;
struct U2 { unsigned long long x, y; };

__device__ __forceinline__ unsigned short f2bf(float f) {
  unsigned int u = __float_as_uint(f);
  u += 0x7fffu + ((u >> 16) & 1u);
  return (unsigned short)(u >> 16);
}
__device__ __forceinline__ float bflo(unsigned int u) { return __uint_as_float(u << 16); }
__device__ __forceinline__ float bfhi(unsigned int u) { return __uint_as_float(u & 0xffff0000u); }

__device__ __forceinline__ void acc8(const U2& v, float* a) {
  unsigned int w0 = (unsigned int)v.x, w1 = (unsigned int)(v.x >> 32);
  unsigned int w2 = (unsigned int)v.y, w3 = (unsigned int)(v.y >> 32);
  a[0] += bflo(w0); a[1] += bfhi(w0); a[2] += bflo(w1); a[3] += bfhi(w1);
  a[4] += bflo(w2); a[5] += bfhi(w2); a[6] += bflo(w3); a[7] += bfhi(w3);
}

// ------------- fused prep+fill: x->bf16, W->bf16 B-frag, bucket-CSR fill --------------
// B-frag slot for 16x16x32: lane=q*16+j16 holds B[k=c*32+q*8+jj][j=jt*16+j16]

__global__ void k_prep_fill(const float* __restrict__ x, unsigned short* __restrict__ hb,
                            const int* __restrict__ ei, int* __restrict__ cnt,
                            int* __restrict__ col, const float* __restrict__ Wl,
                            const float* __restrict__ Wr, unsigned short* __restrict__ Wb,
                            const float* __restrict__ Wf, unsigned short* __restrict__ Wfb) {
  int i = blockIdx.x * 256 + threadIdx.x;
  long long base = (long long)i * 4;
  if (base < (long long)NN * 128) {
    float4 v = *(const float4*)(x + base);
    unsigned long long pk = (unsigned long long)f2bf(v.x) |
                            ((unsigned long long)f2bf(v.y) << 16) |
                            ((unsigned long long)f2bf(v.z) << 32) |
                            ((unsigned long long)f2bf(v.w) << 48);
    *(unsigned long long*)(hb + base) = pk;
  }
  if (i < NE) {
    int d = ei[i];
    int pos = atomicAdd(&cnt[d], 1);
    if (pos < BCAP) col[(size_t)d * BCAP + pos] = ei[NE + i];
  }
  if (i < 3 * 16384) {
    int layer = i >> 14, r = i & 16383;
    int j = r >> 7, k = r & 127;
    int c = k >> 5, q = (k >> 3) & 3, jj = k & 7, jt = j >> 4, j16 = j & 15;
    int slot = (c * 8 + jt) * 512 + (q * 16 + j16) * 8 + jj;
    Wb[layer * 32768 + slot] = f2bf(Wl[i]);
    Wb[layer * 32768 + 16384 + slot] = f2bf(Wr[i]);
  } else if (i < 3 * 16384 + 8192) {
    int idx = i - 3 * 16384;
    int j = idx >> 7, k = idx & 127;
    int c = k >> 5, q = (k >> 3) & 3, jj = k & 7, jt = j >> 4, j16 = j & 15;
    Wfb[(c * 4 + jt) * 512 + (q * 16 + j16) * 8 + jj] = f2bf(Wf[idx]);
  }
}

// ---------------- fused SAGE layer (+ fused final head when LAST) ----------------
// block = 128 threads (2 waves), 32 nodes/block (16/wave). LDS ~8.8KB (no colS!)
// -> occupancy capped only by waves/regs (16 blocks/CU possible).
// Gather: 16-lane group per node; the group's 32 bucket indices are preloaded
// into 2 registers (coalesced) and broadcast per-edge via __shfl -> the
// index fetch is OFF the load-dependency chain. Depth-4 row pipeline, 16B/lane.
template <bool LAST>
__global__ __launch_bounds__(128, 6)
void k_layer(const unsigned short* __restrict__ hin, unsigned short* __restrict__ hout,
             const int* __restrict__ deg, const int* __restrict__ col,
             const unsigned short* __restrict__ Wb, const float* __restrict__ bl,
             const float* __restrict__ gmm, const float* __restrict__ bta,
             const unsigned short* __restrict__ Wfb, const float* __restrict__ bfp,
             float* __restrict__ out) {
  __shared__ int degS[32];                  //  128B
  __shared__ unsigned short aggS[32 * 136]; // 8704B ; overlaid by hS in LAST tail
  const int t = threadIdx.x;
  const int w = t >> 6;
  const int lane = t & 63;
  const int nodeBase = blockIdx.x * 32;
  const int q = lane >> 4;
  const int n16 = lane & 15;

  // prefetch own-row h A-frags (independent of gather)
  int nrow = nodeBase + w * 16 + n16;
  const unsigned short* hrow = hin + (size_t)nrow * 128;
  short8 a_h[4];
#pragma unroll
  for (int c = 0; c < 4; ++c) a_h[c] = *(const short8*)(hrow + c * 32 + q * 8);

  if (t < 32) degS[t] = deg[nodeBase + t];
  __syncthreads();

  // gather: 16-lane group per node (4 concurrent per wave)
  const int grpBase = lane & 48;  // group's base lane in wave
  const int jl = lane & 15;
  auto rowAt = [&](int s) { return *(const U2*)(hin + (size_t)s * 128 + jl * 8); };
#pragma unroll
  for (int mm = 0; mm < 4; ++mm) {
    int li = w * 16 + mm * 4 + (grpBase >> 4);
    int n = nodeBase + li;
    int d = degS[li];
    if (d > BCAP) d = BCAP;
    float inv = 1.f / fmaxf((float)degS[li], 1.f);
    // preload this node's bucket indices into registers (64B coalesced per group)
    int idxA = col[(size_t)n * BCAP + jl];
    int idxB = col[(size_t)n * BCAP + 16 + jl];
    float a[8] = {0.f, 0.f, 0.f, 0.f, 0.f, 0.f, 0.f, 0.f};
    for (int j = 0; j < d; j += 4) {  // j multiple of 4: quad never straddles 16
      int src = (j < 16) ? idxA : idxB;
      int s0 = __shfl(src, grpBase + ((j + 0) & 15), 64);
      int s1 = __shfl(src, grpBase + ((j + 1) & 15), 64);
      int s2 = __shfl(src, grpBase + ((j + 2) & 15), 64);
      int s3 = __shfl(src, grpBase + ((j + 3) & 15), 64);
      U2 v0, v1, v2, v3;
      if (j + 0 < d) v0 = rowAt(s0);
      if (j + 1 < d) v1 = rowAt(s1);
      if (j + 2 < d) v2 = rowAt(s2);
      if (j + 3 < d) v3 = rowAt(s3);
      if (j + 0 < d) acc8(v0, a);
      if (j + 1 < d) acc8(v1, a);
      if (j + 2 < d) acc8(v2, a);
      if (j + 3 < d) acc8(v3, a);
    }
    unsigned int p0 = ((unsigned int)f2bf(a[1] * inv) << 16) | f2bf(a[0] * inv);
    unsigned int p1 = ((unsigned int)f2bf(a[3] * inv) << 16) | f2bf(a[2] * inv);
    unsigned int p2 = ((unsigned int)f2bf(a[5] * inv) << 16) | f2bf(a[4] * inv);
    unsigned int p3 = ((unsigned int)f2bf(a[7] * inv) << 16) | f2bf(a[6] * inv);
    *(uint4*)&aggS[li * 136 + jl * 8] = make_uint4(p0, p1, p2, p3);
  }
  __syncthreads();

  // MFMA: wave handles 16 nodes x 128 out; B-frags from prepped global (L2)
  f32x4 acc[8];
#pragma unroll
  for (int jt = 0; jt < 8; ++jt) acc[jt] = (f32x4){0.f, 0.f, 0.f, 0.f};
  const unsigned short* aggrow = aggS + (w * 16 + n16) * 136;
#pragma unroll
  for (int c = 0; c < 4; ++c) {
    short8 a_agg = *(const short8*)(aggrow + c * 32 + q * 8);
#pragma unroll
    for (int jt = 0; jt < 8; ++jt) {
      short8 b_l = *(const short8*)(Wb + (c * 8 + jt) * 512 + lane * 8);
      short8 b_r = *(const short8*)(Wb + 16384 + (c * 8 + jt) * 512 + lane * 8);
      acc[jt] = __builtin_amdgcn_mfma_f32_16x16x32_bf16(a_agg, b_l, acc[jt], 0, 0, 0);
      acc[jt] = __builtin_amdgcn_mfma_f32_16x16x32_bf16(a_h[c], b_r, acc[jt], 0, 0, 0);
    }
  }

  // epilogue: +bias, LayerNorm (xor-shuffle over 16-lane groups), ReLU
  float blv[8], gv[8], bv[8];
#pragma unroll
  for (int jt = 0; jt < 8; ++jt) {
    int j = jt * 16 + n16;
    blv[jt] = bl[j];
    gv[jt] = gmm[j];
    bv[jt] = bta[j];
  }
  float s[4] = {0, 0, 0, 0}, ss[4] = {0, 0, 0, 0};
#pragma unroll
  for (int jt = 0; jt < 8; ++jt)
#pragma unroll
    for (int r = 0; r < 4; ++r) {
      float v = acc[jt][r] + blv[jt];
      acc[jt][r] = v;
      s[r] += v;
      ss[r] += v * v;
    }
#pragma unroll
  for (int mask = 1; mask < 16; mask <<= 1) {
#pragma unroll
    for (int r = 0; r < 4; ++r) {
      s[r] += __shfl_xor(s[r], mask, 64);
      ss[r] += __shfl_xor(ss[r], mask, 64);
    }
  }
  float mu[4], rs[4];
#pragma unroll
  for (int r = 0; r < 4; ++r) {
    mu[r] = s[r] * (1.f / 128.f);
    float var = ss[r] * (1.f / 128.f) - mu[r] * mu[r];
    rs[r] = rsqrtf(var + 1e-5f);
  }

  if (!LAST) {
#pragma unroll
    for (int jt = 0; jt < 8; ++jt)
#pragma unroll
      for (int r = 0; r < 4; ++r) {
        int n = nodeBase + w * 16 + q * 4 + r;
        float v = (acc[jt][r] - mu[r]) * rs[r] * gv[jt] + bv[jt];
        hout[(size_t)n * 128 + jt * 16 + n16] = f2bf(fmaxf(v, 0.f));
      }
  } else {
    unsigned short* hS = aggS;  // overlay (each wave touches only its own 16 rows)
    __syncthreads();
#pragma unroll
    for (int jt = 0; jt < 8; ++jt)
#pragma unroll
      for (int r = 0; r < 4; ++r) {
        float v = (acc[jt][r] - mu[r]) * rs[r] * gv[jt] + bv[jt];
        hS[(w * 16 + q * 4 + r) * 136 + jt * 16 + n16] = f2bf(fmaxf(v, 0.f));
      }
    // final 128x64 GEMM + log_softmax (same-wave rows only)
    f32x4 acc2[4];
#pragma unroll
    for (int jt = 0; jt < 4; ++jt) acc2[jt] = (f32x4){0.f, 0.f, 0.f, 0.f};
#pragma unroll
    for (int c = 0; c < 4; ++c) {
      short8 a3 = *(const short8*)&hS[(w * 16 + n16) * 136 + c * 32 + q * 8];
#pragma unroll
      for (int jt = 0; jt < 4; ++jt) {
        short8 b = *(const short8*)(Wfb + (c * 4 + jt) * 512 + lane * 8);
        acc2[jt] = __builtin_amdgcn_mfma_f32_16x16x32_bf16(a3, b, acc2[jt], 0, 0, 0);
      }
    }
    float bfv[4];
#pragma unroll
    for (int jt = 0; jt < 4; ++jt) bfv[jt] = bfp[jt * 16 + n16];
    float mx[4] = {-1e30f, -1e30f, -1e30f, -1e30f};
#pragma unroll
    for (int jt = 0; jt < 4; ++jt)
#pragma unroll
      for (int r = 0; r < 4; ++r) {
        float v = acc2[jt][r] + bfv[jt];
        acc2[jt][r] = v;
        mx[r] = fmaxf(mx[r], v);
      }
#pragma unroll
    for (int mask = 1; mask < 16; mask <<= 1)
#pragma unroll
      for (int r = 0; r < 4; ++r) mx[r] = fmaxf(mx[r], __shfl_xor(mx[r], mask, 64));
    float se[4] = {0, 0, 0, 0};
#pragma unroll
    for (int jt = 0; jt < 4; ++jt)
#pragma unroll
      for (int r = 0; r < 4; ++r) se[r] += expf(acc2[jt][r] - mx[r]);
#pragma unroll
    for (int mask = 1; mask < 16; mask <<= 1)
#pragma unroll
      for (int r = 0; r < 4; ++r) se[r] += __shfl_xor(se[r], mask, 64);
    float lse[4];
#pragma unroll
    for (int r = 0; r < 4; ++r) lse[r] = mx[r] + logf(se[r]);
#pragma unroll
    for (int jt = 0; jt < 4; ++jt)
#pragma unroll
      for (int r = 0; r < 4; ++r) {
        int n = nodeBase + w * 16 + q * 4 + r;
        out[(size_t)n * 64 + jt * 16 + n16] = acc2[jt][r] - lse[r];
      }
  }
}

// ---------------- launch ----------------

extern "C" void kernel_launch(void* const* d_in, const int* in_sizes, int n_in,
                              void* d_out, int out_size, void* d_ws, size_t ws_size,
                              hipStream_t stream) {
  const float* x = (const float*)d_in[0];
  const int* ei = (const int*)d_in[1];
  const float* Wl = (const float*)d_in[2];
  const float* bl = (const float*)d_in[3];
  const float* Wr = (const float*)d_in[4];
  const float* gmm = (const float*)d_in[5];
  const float* bta = (const float*)d_in[6];
  const float* Wf = (const float*)d_in[7];
  const float* bfp = (const float*)d_in[8];

  char* ws = (char*)d_ws;
  size_t off = 0;
  auto alloc = [&](size_t bytes) {
    void* p = ws + off;
    off = (off + bytes + 255) & ~(size_t)255;
    return p;
  };
  int* cnt = (int*)alloc((size_t)(NN + 32) * 4);          // degree (atomic cursor)
  int* col = (int*)alloc((size_t)(NN + 32) * BCAP * 4);   // bucketed CSR
  unsigned short* hb0 = (unsigned short*)alloc((size_t)NN * 128 * 2);
  unsigned short* hb1 = (unsigned short*)alloc((size_t)NN * 128 * 2);
  unsigned short* Wb = (unsigned short*)alloc((size_t)3 * 32768 * 2);
  unsigned short* Wfb = (unsigned short*)alloc((size_t)8192 * 2);

  hipMemsetAsync(cnt, 0, (size_t)(NN + 32) * 4, stream);
  k_prep_fill<<<(NN * 128 / 4 + 255) / 256, 256, 0, stream>>>(x, hb0, ei, cnt, col, Wl,
                                                              Wr, Wb, Wf, Wfb);

  k_layer<false><<<NBT, 128, 0, stream>>>(hb0, hb1, cnt, col, Wb, bl, gmm, bta, Wfb, bfp,
                                          (float*)d_out);
  k_layer<false><<<NBT, 128, 0, stream>>>(hb1, hb0, cnt, col, Wb + 32768, bl + 128,
                                          gmm + 128, bta + 128, Wfb, bfp, (float*)d_out);
  k_layer<true><<<NBT, 128, 0, stream>>>(hb0, hb1, cnt, col, Wb + 65536, bl + 256,
                                         gmm + 256, bta + 256, Wfb, bfp, (float*)d_out);
}

// Round 12
// 315.118 us; speedup vs baseline: 1.4115x; 1.0257x over previous
//
#include <hip/hip_runtime.h>

#define NN 100000
#define NE 800000
#define BCAP 32  // bucket capacity per dst; deg ~ Poisson(8), P(deg>32) ~ 2.5e-11/node

static constexpr int NBT = NN / 32;  // node-tile blocks (32 nodes) = 3125, exact

typedef __attribute__((ext_vector_type(8))) short short8;
typedef __attribute__((ext_vector_type(4))) float f32x4;
struct U2 { unsigned long long x, y; };

__device__ __forceinline__ unsigned short f2bf(float f) {
  unsigned int u = __float_as_uint(f);
  u += 0x7fffu + ((u >> 16) & 1u);
  return (unsigned short)(u >> 16);
}
__device__ __forceinline__ float bflo(unsigned int u) { return __uint_as_float(u << 16); }
__device__ __forceinline__ float bfhi(unsigned int u) { return __uint_as_float(u & 0xffff0000u); }

__device__ __forceinline__ void acc8(const U2& v, float* a) {
  unsigned int w0 = (unsigned int)v.x, w1 = (unsigned int)(v.x >> 32);
  unsigned int w2 = (unsigned int)v.y, w3 = (unsigned int)(v.y >> 32);
  a[0] += bflo(w0); a[1] += bfhi(w0); a[2] += bflo(w1); a[3] += bfhi(w1);
  a[4] += bflo(w2); a[5] += bfhi(w2); a[6] += bflo(w3); a[7] += bfhi(w3);
}

// ------------- fused prep+fill: x->bf16, W->bf16 B-frag, bucket-CSR fill --------------
// Also zeroes the dummy row NN of both h buffers (branchless-gather target).

__global__ void k_prep_fill(const float* __restrict__ x, unsigned short* __restrict__ hb,
                            unsigned short* __restrict__ hb1, const int* __restrict__ ei,
                            int* __restrict__ cnt, int* __restrict__ col,
                            const float* __restrict__ Wl, const float* __restrict__ Wr,
                            unsigned short* __restrict__ Wb, const float* __restrict__ Wf,
                            unsigned short* __restrict__ Wfb) {
  int i = blockIdx.x * 256 + threadIdx.x;
  long long base = (long long)i * 4;
  if (base < (long long)NN * 128) {
    float4 v = *(const float4*)(x + base);
    unsigned long long pk = (unsigned long long)f2bf(v.x) |
                            ((unsigned long long)f2bf(v.y) << 16) |
                            ((unsigned long long)f2bf(v.z) << 32) |
                            ((unsigned long long)f2bf(v.w) << 48);
    *(unsigned long long*)(hb + base) = pk;
  } else if (i < NN * 32 + 64) {
    // zero dummy row NN in both buffers (i in [NN*32, NN*32+64))
    int k = i - NN * 32;
    unsigned long long* dst = (k < 32) ? (unsigned long long*)(hb + (size_t)NN * 128)
                                       : (unsigned long long*)(hb1 + (size_t)NN * 128);
    dst[k & 31] = 0ull;
  }
  if (i < NE) {
    int d = ei[i];
    int pos = atomicAdd(&cnt[d], 1);
    if (pos < BCAP) col[(size_t)d * BCAP + pos] = ei[NE + i];
  }
  if (i < 3 * 16384) {
    int layer = i >> 14, r = i & 16383;
    int j = r >> 7, k = r & 127;
    int c = k >> 5, q = (k >> 3) & 3, jj = k & 7, jt = j >> 4, j16 = j & 15;
    int slot = (c * 8 + jt) * 512 + (q * 16 + j16) * 8 + jj;
    Wb[layer * 32768 + slot] = f2bf(Wl[i]);
    Wb[layer * 32768 + 16384 + slot] = f2bf(Wr[i]);
  } else if (i < 3 * 16384 + 8192) {
    int idx = i - 3 * 16384;
    int j = idx >> 7, k = idx & 127;
    int c = k >> 5, q = (k >> 3) & 3, jj = k & 7, jt = j >> 4, j16 = j & 15;
    Wfb[(c * 4 + jt) * 512 + (q * 16 + j16) * 8 + jj] = f2bf(Wf[idx]);
  }
}

// ---------------- fused SAGE layer (+ fused final head when LAST) ----------------
// block = 128 threads (2 waves), 32 nodes/block (16/wave). LDS ~8.8KB.
// Gather: 16-lane group per node; 32 bucket indices preloaded into 2 registers,
// broadcast via __shfl. BRANCHLESS: lanes past d redirect to the zero row NN, so
// each iteration issues 8 UNCONDITIONAL loads (one waitcnt per 8, 8KB in
// flight/wave). 59% of nodes (deg<=8) finish in one iteration.
template <bool LAST>
__global__ __launch_bounds__(128, 6)
void k_layer(const unsigned short* __restrict__ hin, unsigned short* __restrict__ hout,
             const int* __restrict__ deg, const int* __restrict__ col,
             const unsigned short* __restrict__ Wb, const float* __restrict__ bl,
             const float* __restrict__ gmm, const float* __restrict__ bta,
             const unsigned short* __restrict__ Wfb, const float* __restrict__ bfp,
             float* __restrict__ out) {
  __shared__ int degS[32];                  //  128B
  __shared__ unsigned short aggS[32 * 136]; // 8704B ; overlaid by hS in LAST tail
  const int t = threadIdx.x;
  const int w = t >> 6;
  const int lane = t & 63;
  const int nodeBase = blockIdx.x * 32;
  const int q = lane >> 4;
  const int n16 = lane & 15;

  // prefetch own-row h A-frags (independent of gather)
  int nrow = nodeBase + w * 16 + n16;
  const unsigned short* hrow = hin + (size_t)nrow * 128;
  short8 a_h[4];
#pragma unroll
  for (int c = 0; c < 4; ++c) a_h[c] = *(const short8*)(hrow + c * 32 + q * 8);

  if (t < 32) degS[t] = deg[nodeBase + t];
  __syncthreads();

  // gather: 16-lane group per node (4 concurrent per wave)
  const int grpBase = lane & 48;  // group's base lane in wave
  const int jl = lane & 15;
  auto rowAt = [&](int s) { return *(const U2*)(hin + (size_t)s * 128 + jl * 8); };
#pragma unroll
  for (int mm = 0; mm < 4; ++mm) {
    int li = w * 16 + mm * 4 + (grpBase >> 4);
    int n = nodeBase + li;
    int d = degS[li];
    if (d > BCAP) d = BCAP;
    float inv = 1.f / fmaxf((float)degS[li], 1.f);
    // preload this node's bucket indices into registers (coalesced per group)
    int idxA = col[(size_t)n * BCAP + jl];
    int idxB = col[(size_t)n * BCAP + 16 + jl];
    float a[8] = {0.f, 0.f, 0.f, 0.f, 0.f, 0.f, 0.f, 0.f};
    for (int j = 0; j < d; j += 8) {  // 8-blocks never straddle the 16 boundary
      int srcReg = (j < 16) ? idxA : idxB;
      int s[8];
#pragma unroll
      for (int i = 0; i < 8; ++i) {
        int si = __shfl(srcReg, grpBase + ((j + i) & 15), 64);
        s[i] = (j + i < d) ? si : NN;  // branchless: pad to zero row
      }
      U2 v[8];
#pragma unroll
      for (int i = 0; i < 8; ++i) v[i] = rowAt(s[i]);  // 8 unconditional loads
#pragma unroll
      for (int i = 0; i < 8; ++i) acc8(v[i], a);
    }
    unsigned int p0 = ((unsigned int)f2bf(a[1] * inv) << 16) | f2bf(a[0] * inv);
    unsigned int p1 = ((unsigned int)f2bf(a[3] * inv) << 16) | f2bf(a[2] * inv);
    unsigned int p2 = ((unsigned int)f2bf(a[5] * inv) << 16) | f2bf(a[4] * inv);
    unsigned int p3 = ((unsigned int)f2bf(a[7] * inv) << 16) | f2bf(a[6] * inv);
    *(uint4*)&aggS[li * 136 + jl * 8] = make_uint4(p0, p1, p2, p3);
  }
  __syncthreads();

  // MFMA: wave handles 16 nodes x 128 out; B-frags from prepped global (L2)
  f32x4 acc[8];
#pragma unroll
  for (int jt = 0; jt < 8; ++jt) acc[jt] = (f32x4){0.f, 0.f, 0.f, 0.f};
  const unsigned short* aggrow = aggS + (w * 16 + n16) * 136;
#pragma unroll
  for (int c = 0; c < 4; ++c) {
    short8 a_agg = *(const short8*)(aggrow + c * 32 + q * 8);
#pragma unroll
    for (int jt = 0; jt < 8; ++jt) {
      short8 b_l = *(const short8*)(Wb + (c * 8 + jt) * 512 + lane * 8);
      short8 b_r = *(const short8*)(Wb + 16384 + (c * 8 + jt) * 512 + lane * 8);
      acc[jt] = __builtin_amdgcn_mfma_f32_16x16x32_bf16(a_agg, b_l, acc[jt], 0, 0, 0);
      acc[jt] = __builtin_amdgcn_mfma_f32_16x16x32_bf16(a_h[c], b_r, acc[jt], 0, 0, 0);
    }
  }

  // epilogue: +bias, LayerNorm (xor-shuffle over 16-lane groups), ReLU
  float blv[8], gv[8], bv[8];
#pragma unroll
  for (int jt = 0; jt < 8; ++jt) {
    int j = jt * 16 + n16;
    blv[jt] = bl[j];
    gv[jt] = gmm[j];
    bv[jt] = bta[j];
  }
  float s[4] = {0, 0, 0, 0}, ss[4] = {0, 0, 0, 0};
#pragma unroll
  for (int jt = 0; jt < 8; ++jt)
#pragma unroll
    for (int r = 0; r < 4; ++r) {
      float v = acc[jt][r] + blv[jt];
      acc[jt][r] = v;
      s[r] += v;
      ss[r] += v * v;
    }
#pragma unroll
  for (int mask = 1; mask < 16; mask <<= 1) {
#pragma unroll
    for (int r = 0; r < 4; ++r) {
      s[r] += __shfl_xor(s[r], mask, 64);
      ss[r] += __shfl_xor(ss[r], mask, 64);
    }
  }
  float mu[4], rs[4];
#pragma unroll
  for (int r = 0; r < 4; ++r) {
    mu[r] = s[r] * (1.f / 128.f);
    float var = ss[r] * (1.f / 128.f) - mu[r] * mu[r];
    rs[r] = rsqrtf(var + 1e-5f);
  }

  if (!LAST) {
#pragma unroll
    for (int jt = 0; jt < 8; ++jt)
#pragma unroll
      for (int r = 0; r < 4; ++r) {
        int n = nodeBase + w * 16 + q * 4 + r;
        float v = (acc[jt][r] - mu[r]) * rs[r] * gv[jt] + bv[jt];
        hout[(size_t)n * 128 + jt * 16 + n16] = f2bf(fmaxf(v, 0.f));
      }
  } else {
    unsigned short* hS = aggS;  // overlay (each wave touches only its own 16 rows)
    __syncthreads();
#pragma unroll
    for (int jt = 0; jt < 8; ++jt)
#pragma unroll
      for (int r = 0; r < 4; ++r) {
        float v = (acc[jt][r] - mu[r]) * rs[r] * gv[jt] + bv[jt];
        hS[(w * 16 + q * 4 + r) * 136 + jt * 16 + n16] = f2bf(fmaxf(v, 0.f));
      }
    // final 128x64 GEMM + log_softmax (same-wave rows only)
    f32x4 acc2[4];
#pragma unroll
    for (int jt = 0; jt < 4; ++jt) acc2[jt] = (f32x4){0.f, 0.f, 0.f, 0.f};
#pragma unroll
    for (int c = 0; c < 4; ++c) {
      short8 a3 = *(const short8*)&hS[(w * 16 + n16) * 136 + c * 32 + q * 8];
#pragma unroll
      for (int jt = 0; jt < 4; ++jt) {
        short8 b = *(const short8*)(Wfb + (c * 4 + jt) * 512 + lane * 8);
        acc2[jt] = __builtin_amdgcn_mfma_f32_16x16x32_bf16(a3, b, acc2[jt], 0, 0, 0);
      }
    }
    float bfv[4];
#pragma unroll
    for (int jt = 0; jt < 4; ++jt) bfv[jt] = bfp[jt * 16 + n16];
    float mx[4] = {-1e30f, -1e30f, -1e30f, -1e30f};
#pragma unroll
    for (int jt = 0; jt < 4; ++jt)
#pragma unroll
      for (int r = 0; r < 4; ++r) {
        float v = acc2[jt][r] + bfv[jt];
        acc2[jt][r] = v;
        mx[r] = fmaxf(mx[r], v);
      }
#pragma unroll
    for (int mask = 1; mask < 16; mask <<= 1)
#pragma unroll
      for (int r = 0; r < 4; ++r) mx[r] = fmaxf(mx[r], __shfl_xor(mx[r], mask, 64));
    float se[4] = {0, 0, 0, 0};
#pragma unroll
    for (int jt = 0; jt < 4; ++jt)
#pragma unroll
      for (int r = 0; r < 4; ++r) se[r] += expf(acc2[jt][r] - mx[r]);
#pragma unroll
    for (int mask = 1; mask < 16; mask <<= 1)
#pragma unroll
      for (int r = 0; r < 4; ++r) se[r] += __shfl_xor(se[r], mask, 64);
    float lse[4];
#pragma unroll
    for (int r = 0; r < 4; ++r) lse[r] = mx[r] + logf(se[r]);
#pragma unroll
    for (int jt = 0; jt < 4; ++jt)
#pragma unroll
      for (int r = 0; r < 4; ++r) {
        int n = nodeBase + w * 16 + q * 4 + r;
        out[(size_t)n * 64 + jt * 16 + n16] = acc2[jt][r] - lse[r];
      }
  }
}

// ---------------- launch ----------------

extern "C" void kernel_launch(void* const* d_in, const int* in_sizes, int n_in,
                              void* d_out, int out_size, void* d_ws, size_t ws_size,
                              hipStream_t stream) {
  const float* x = (const float*)d_in[0];
  const int* ei = (const int*)d_in[1];
  const float* Wl = (const float*)d_in[2];
  const float* bl = (const float*)d_in[3];
  const float* Wr = (const float*)d_in[4];
  const float* gmm = (const float*)d_in[5];
  const float* bta = (const float*)d_in[6];
  const float* Wf = (const float*)d_in[7];
  const float* bfp = (const float*)d_in[8];

  char* ws = (char*)d_ws;
  size_t off = 0;
  auto alloc = [&](size_t bytes) {
    void* p = ws + off;
    off = (off + bytes + 255) & ~(size_t)255;
    return p;
  };
  int* cnt = (int*)alloc((size_t)(NN + 32) * 4);          // degree (atomic cursor)
  int* col = (int*)alloc((size_t)(NN + 32) * BCAP * 4);   // bucketed CSR
  unsigned short* hb0 = (unsigned short*)alloc((size_t)(NN + 1) * 128 * 2);  // +zero row
  unsigned short* hb1 = (unsigned short*)alloc((size_t)(NN + 1) * 128 * 2);  // +zero row
  unsigned short* Wb = (unsigned short*)alloc((size_t)3 * 32768 * 2);
  unsigned short* Wfb = (unsigned short*)alloc((size_t)8192 * 2);

  hipMemsetAsync(cnt, 0, (size_t)(NN + 32) * 4, stream);
  k_prep_fill<<<(NN * 128 / 4 + 255) / 256, 256, 0, stream>>>(x, hb0, hb1, ei, cnt, col,
                                                              Wl, Wr, Wb, Wf, Wfb);

  k_layer<false><<<NBT, 128, 0, stream>>>(hb0, hb1, cnt, col, Wb, bl, gmm, bta, Wfb, bfp,
                                          (float*)d_out);
  k_layer<false><<<NBT, 128, 0, stream>>>(hb1, hb0, cnt, col, Wb + 32768, bl + 128,
                                          gmm + 128, bta + 128, Wfb, bfp, (float*)d_out);
  k_layer<true><<<NBT, 128, 0, stream>>>(hb0, hb1, cnt, col, Wb + 65536, bl + 256,
                                         gmm + 256, bta + 256, Wfb, bfp, (float*)d_out);
}